// Round 4
// baseline (196.384 us; speedup 1.0000x reference)
//
#include <hip/hip_runtime.h>

#define DIMK 64
#define MC 256
#define BR 64                    // rows per block
#define NROWS 262144
#define NB (NROWS / BR)          // 4096 blocks

// workspace layout (bytes):
//   [0, 1024)            cvec fp32 (256 floats)            [always]
//   [1024, 1024+65536)   At fp16 hi/lo image (fast path only, ws_size-guarded):
//     col n (0..255) at byte 1024 + n*256; within a column:
//       s*128 + kc*32 + half*16,  kc = 2*ksl + hi,  half: 0=hi,1=lo
//     j-th element of the half8 is k = s*32 + kc*8 + j
#define WS_AT 1024
#define WS_NEED (1024 + 65536)

// false-path LDS offsets (round-3 proven layout)
#define LDS_AH 0
#define LDS_AL 16384
#define LDS_GM 32768             // [2 rg][32 row][2 cg] floats = 512 B
// fast-path LDS offsets
#define LDS_ZT 0                 // [64 rows][256 B] fp32 z tile, chunk16 ^= (row&15)
#define LDS_GM2 16384

typedef _Float16 half8 __attribute__((ext_vector_type(8)));
typedef float f32x16 __attribute__((ext_vector_type(16)));

// cvec only (1 KB ws — proven-safe footprint)
__global__ void precompute_c(const float* __restrict__ pivot,
                             const float* __restrict__ At,
                             float* __restrict__ ws) {
    const int t = threadIdx.x;
    float acc = 0.f;
#pragma unroll
    for (int k = 0; k < DIMK; ++k) acc = fmaf(pivot[k], At[k * MC + t], acc);
    ws[t] = acc;
}

// cvec + one-time At -> fp16 hi/lo split, column-blocked image (fast path)
__global__ void precompute_at(const float* __restrict__ pivot,
                              const float* __restrict__ At,
                              float* __restrict__ ws) {
    const int t = threadIdx.x;              // column 0..255
    float col[DIMK];
    float acc = 0.f;
#pragma unroll
    for (int k = 0; k < DIMK; ++k) {
        col[k] = At[k * MC + t];            // coalesced across t
        acc = fmaf(pivot[k], col[k], acc);
    }
    ws[t] = acc;                            // cvec, fp32
    char* wsb = (char*)ws + WS_AT + t * 256;
#pragma unroll
    for (int s = 0; s < 2; ++s) {
#pragma unroll
        for (int kc = 0; kc < 4; ++kc) {
            half8 h, l;
#pragma unroll
            for (int j = 0; j < 8; ++j) {
                const float v = col[s * 32 + kc * 8 + j];
                h[j] = (_Float16)v;
                l[j] = (_Float16)(v - (float)h[j]);
            }
            *(half8*)(wsb + s * 128 + kc * 32) = h;
            *(half8*)(wsb + s * 128 + kc * 32 + 16) = l;
        }
    }
}

template <bool PREAT>
__global__ __launch_bounds__(256, 4)
void fused_constrain_mfma(const float* __restrict__ z,
                          const float* __restrict__ pivot,
                          const float* __restrict__ At,
                          const float* __restrict__ b,
                          const float* __restrict__ ws,
                          float* __restrict__ out) {
    __shared__ __align__(16) char lds[33280];

    const int tid  = threadIdx.x;
    const int lane = tid & 63;
    const int li   = lane & 31;          // tile col lane (B) / tile row (A)
    const int hi   = lane >> 5;          // k-half within 16-k step
    const int wid  = tid >> 6;
    const int rg   = wid >> 1;           // row group: rows rg*32..+32
    const int cg   = wid & 1;            // col group: cols cg*128..+128
    const int R0   = rg * 32;
    const int colbase = cg * 128;
    const int base = blockIdx.x * (BR * DIMK);

    // ---- z A-fragment loads (rows owned per-lane, both k-steps) ----
    float4 zf[8];
    {
        const float* zr = z + base + (R0 + li) * DIMK + hi * 8;
#pragma unroll
        for (int q = 0; q < 4; ++q) {            // q = s*2 + ksl
            const float* p = zr + (q >> 1) * 32 + (q & 1) * 16;
            zf[q * 2 + 0] = *(const float4*)(p);
            zf[q * 2 + 1] = *(const float4*)(p + 4);
        }
    }

    if constexpr (PREAT) {
        // fast path: park exact fp32 z in LDS for the epilogue (swizzled)
        const int zrow = R0 + li;
        const int rx = zrow & 15;
        char* zt = lds + LDS_ZT + zrow * 256;
#pragma unroll
        for (int q = 0; q < 4; ++q) {
            const int c0 = hi * 2 + (q >> 1) * 8 + (q & 1) * 4;  // chunk16 idx
            *(float4*)(zt + ((c0 ^ rx) << 4))       = zf[q * 2 + 0];
            *(float4*)(zt + (((c0 + 1) ^ rx) << 4)) = zf[q * 2 + 1];
        }
    } else {
        // fallback: stage At step 0 into LDS (round-3 proven path)
        const int swzT = (tid & 3) ^ ((tid >> 2) & 3);
#pragma unroll
        for (int kc = 0; kc < 4; ++kc) {
            float v[8];
#pragma unroll
            for (int j = 0; j < 8; ++j)
                v[j] = At[(kc * 8 + j) * MC + tid];
            half8 h, l;
#pragma unroll
            for (int j = 0; j < 8; ++j) {
                h[j] = (_Float16)v[j];
                l[j] = (_Float16)(v[j] - (float)h[j]);
            }
            const int off = tid * 64 + ((kc ^ swzT) << 4);
            *(half8*)(lds + LDS_AH + off) = h;
            *(half8*)(lds + LDS_AL + off) = l;
        }
    }

    // ---- convert z to fp16 hi/lo fragments ----
    half8 azh[4], azl[4];
    const float* zv = (const float*)zf;
#pragma unroll
    for (int q = 0; q < 4; ++q)
#pragma unroll
        for (int j = 0; j < 8; ++j) {
            const float v = zv[q * 8 + j];
            azh[q][j] = (_Float16)v;
            azl[q][j] = (_Float16)(v - (float)azh[q][j]);
        }

    f32x16 acc[4];
#pragma unroll
    for (int ct = 0; ct < 4; ++ct)
#pragma unroll
        for (int e = 0; e < 16; ++e) acc[ct][e] = 0.f;

    if constexpr (PREAT) {
        // ---- barrier-free GEMM: B fragments straight from L1/L2-hot ws image ----
        const char* p[4];
#pragma unroll
        for (int ct = 0; ct < 4; ++ct)
            p[ct] = (const char*)ws + WS_AT +
                    (colbase + ct * 32 + li) * 256 + hi * 32;
#pragma unroll
        for (int s = 0; s < 2; ++s)
#pragma unroll
            for (int ksl = 0; ksl < 2; ++ksl) {
                const half8 ah = azh[s * 2 + ksl], al = azl[s * 2 + ksl];
#pragma unroll
                for (int ct = 0; ct < 4; ++ct) {
                    const half8 bh = *(const half8*)(p[ct] + s * 128 + ksl * 64);
                    const half8 bl = *(const half8*)(p[ct] + s * 128 + ksl * 64 + 16);
                    acc[ct] = __builtin_amdgcn_mfma_f32_32x32x16_f16(ah, bh, acc[ct], 0, 0, 0);
                    acc[ct] = __builtin_amdgcn_mfma_f32_32x32x16_f16(ah, bl, acc[ct], 0, 0, 0);
                    acc[ct] = __builtin_amdgcn_mfma_f32_32x32x16_f16(al, bh, acc[ct], 0, 0, 0);
                }
            }
    } else {
        // ---- fallback: two staged phases with barriers (round-3 verbatim) ----
        const int swz = (li & 3) ^ ((li >> 2) & 3);
        __syncthreads();
#pragma unroll
        for (int ksl = 0; ksl < 2; ++ksl) {
            const int cb = ((ksl * 2 + hi) ^ swz) << 4;
            const half8 ah = azh[ksl], al = azl[ksl];
#pragma unroll
            for (int ct = 0; ct < 4; ++ct) {
                const int off = (colbase + ct * 32 + li) * 64 + cb;
                const half8 bh = *(const half8*)(lds + LDS_AH + off);
                const half8 bl = *(const half8*)(lds + LDS_AL + off);
                acc[ct] = __builtin_amdgcn_mfma_f32_32x32x16_f16(ah, bh, acc[ct], 0, 0, 0);
                acc[ct] = __builtin_amdgcn_mfma_f32_32x32x16_f16(ah, bl, acc[ct], 0, 0, 0);
                acc[ct] = __builtin_amdgcn_mfma_f32_32x32x16_f16(al, bh, acc[ct], 0, 0, 0);
            }
        }
        __syncthreads();
        const int swzT = (tid & 3) ^ ((tid >> 2) & 3);
#pragma unroll
        for (int kc = 0; kc < 4; ++kc) {
            float v[8];
#pragma unroll
            for (int j = 0; j < 8; ++j)
                v[j] = At[(32 + kc * 8 + j) * MC + tid];
            half8 h, l;
#pragma unroll
            for (int j = 0; j < 8; ++j) {
                h[j] = (_Float16)v[j];
                l[j] = (_Float16)(v[j] - (float)h[j]);
            }
            const int off = tid * 64 + ((kc ^ swzT) << 4);
            *(half8*)(lds + LDS_AH + off) = h;
            *(half8*)(lds + LDS_AL + off) = l;
        }
        __syncthreads();
#pragma unroll
        for (int ksl = 0; ksl < 2; ++ksl) {
            const int cb = ((ksl * 2 + hi) ^ swz) << 4;
            const half8 ah = azh[2 + ksl], al = azl[2 + ksl];
#pragma unroll
            for (int ct = 0; ct < 4; ++ct) {
                const int off = (colbase + ct * 32 + li) * 64 + cb;
                const half8 bh = *(const half8*)(lds + LDS_AH + off);
                const half8 bl = *(const half8*)(lds + LDS_AL + off);
                acc[ct] = __builtin_amdgcn_mfma_f32_32x32x16_f16(ah, bh, acc[ct], 0, 0, 0);
                acc[ct] = __builtin_amdgcn_mfma_f32_32x32x16_f16(ah, bl, acc[ct], 0, 0, 0);
                acc[ct] = __builtin_amdgcn_mfma_f32_32x32x16_f16(al, bh, acc[ct], 0, 0, 0);
            }
        }
    }

    // ---- epilogue: masked alpha, intra-wave col-max, cross-wave combine ----
    float bv[4], cv[4];
#pragma unroll
    for (int ct = 0; ct < 4; ++ct) {
        const int c = colbase + ct * 32 + li;
        bv[ct] = b[c];
        cv[ct] = ws[c];                 // cvec (fp32)
    }
    float gm[16];
#pragma unroll
    for (int r = 0; r < 16; ++r) gm[r] = 0.f;
#pragma unroll
    for (int ct = 0; ct < 4; ++ct)
#pragma unroll
        for (int r = 0; r < 16; ++r) {
            const float sv = acc[ct][r];
            const float sa = sv - bv[ct];
            const float qd = fmaxf(sv - cv[ct], 1e-9f);
            // sa<0 gives negative alpha, excluded by fmax against gm>=0
            gm[r] = fmaxf(gm[r], sa * __builtin_amdgcn_rcpf(qd));
        }
#pragma unroll
    for (int r = 0; r < 16; ++r)
#pragma unroll
        for (int off = 1; off < 32; off <<= 1)   // reduce over 32 col-lanes
            gm[r] = fmaxf(gm[r], __shfl_xor(gm[r], off));

    float* gmbuf = (float*)(lds + (PREAT ? LDS_GM2 : LDS_GM));
#pragma unroll
    for (int r = 0; r < 16; ++r) {
        const int row = (r & 3) + 8 * (r >> 2) + 4 * hi;   // C/D row map
        if (li == 0) gmbuf[rg * 64 + row * 2 + cg] = gm[r];
    }
    __syncthreads();   // covers gmbuf and (fast path) z-tile visibility

    // cg0 stores rows R0+0..15 (its r 0..7), cg1 stores rows R0+16..31
    const float2 p2 = *(const float2*)(pivot + 2 * li);
    const int r0 = cg * 8;
#pragma unroll
    for (int rr = 0; rr < 8; ++rr) {
        const int r   = r0 + rr;
        const int row = (r & 3) + 8 * (r >> 2) + 4 * hi;
        const float g = fmaxf(gm[r], gmbuf[rg * 64 + row * 2 + (cg ^ 1)]);
        const int zrow = R0 + row;
        float2 zz;
        if constexpr (PREAT) {
            const int byt = LDS_ZT + zrow * 256 +
                            (((li >> 1) ^ (zrow & 15)) << 4) + (li & 1) * 8;
            zz = *(const float2*)(lds + byt);        // exact fp32 z from LDS
        } else {
            zz = *(const float2*)(z + base + zrow * DIMK + 2 * li);
        }
        float2 o;
        o.x = fmaf(g, p2.x - zz.x, zz.x);
        o.y = fmaf(g, p2.y - zz.y, zz.y);
        *(float2*)(out + base + zrow * DIMK + 2 * li) = o;
    }
}

extern "C" void kernel_launch(void* const* d_in, const int* in_sizes, int n_in,
                              void* d_out, int out_size, void* d_ws, size_t ws_size,
                              hipStream_t stream) {
    const float* z     = (const float*)d_in[0];
    const float* pivot = (const float*)d_in[1];
    const float* At    = (const float*)d_in[2];
    const float* b     = (const float*)d_in[3];
    float* ws = (float*)d_ws;
    if (ws_size >= (size_t)WS_NEED) {
        // fast path: pre-split At image lives in workspace; barrier-free GEMM
        precompute_at<<<dim3(1), dim3(MC), 0, stream>>>(pivot, At, ws);
        fused_constrain_mfma<true><<<dim3(NB), dim3(256), 0, stream>>>(
            z, pivot, At, b, ws, (float*)d_out);
    } else {
        // safe path: only 1 KB of workspace (cvec); At split done per-block
        precompute_c<<<dim3(1), dim3(MC), 0, stream>>>(pivot, At, ws);
        fused_constrain_mfma<false><<<dim3(NB), dim3(256), 0, stream>>>(
            z, pivot, At, b, ws, (float*)d_out);
    }
}

// Round 5
// 161.438 us; speedup vs baseline: 1.2165x; 1.2165x over previous
//
#include <hip/hip_runtime.h>

#define DIMK 64
#define MC 256
#define BR 64                    // rows per block
#define NROWS 262144
#define NB (NROWS / BR)          // 4096 blocks

// workspace layout (bytes):
//   [0, 1024)            cvec fp32 (256 floats)            [always]
//   [1024, 1024+65536)   At fp16 hi/lo image (fast path only, ws_size-guarded):
//     plane-major for coalesced fragment loads:
//       hi-half: WS_AT + ((s*4 + kc)*256 + col)*16,  kc = 2*ksl + hi
//       lo-half: +32768
//     j-th half of a 16B chunk is k = s*32 + kc*8 + j
#define WS_AT 1024
#define WS_NEED (1024 + 65536)

// fallback-path LDS offsets (round-3 proven layout)
#define LDS_AH 0
#define LDS_AL 16384
#define LDS_GM 32768             // [2 rg][32 row][2 cg] floats = 512 B
// fast-path LDS offsets
#define LDS_ZT 0                 // [64 rows][256 B] fp32 z tile, chunk16 ^= (row&15)
#define LDS_GM2 16384

typedef _Float16 half8 __attribute__((ext_vector_type(8)));
typedef float f32x16 __attribute__((ext_vector_type(16)));

// cvec only (1 KB ws — proven-safe footprint)
__global__ void precompute_c(const float* __restrict__ pivot,
                             const float* __restrict__ At,
                             float* __restrict__ ws) {
    const int t = threadIdx.x;
    float acc = 0.f;
#pragma unroll
    for (int k = 0; k < DIMK; ++k) acc = fmaf(pivot[k], At[k * MC + t], acc);
    ws[t] = acc;
}

// cvec + one-time At -> fp16 hi/lo split, plane-major image (fast path)
__global__ void precompute_at(const float* __restrict__ pivot,
                              const float* __restrict__ At,
                              float* __restrict__ ws) {
    const int t = threadIdx.x;              // column 0..255
    float col[DIMK];
    float acc = 0.f;
#pragma unroll
    for (int k = 0; k < DIMK; ++k) {
        col[k] = At[k * MC + t];            // coalesced across t
        acc = fmaf(pivot[k], col[k], acc);
    }
    ws[t] = acc;                            // cvec, fp32
    char* wsb = (char*)ws + WS_AT;
#pragma unroll
    for (int s = 0; s < 2; ++s) {
#pragma unroll
        for (int kc = 0; kc < 4; ++kc) {
            half8 h, l;
#pragma unroll
            for (int j = 0; j < 8; ++j) {
                const float v = col[s * 32 + kc * 8 + j];
                h[j] = (_Float16)v;
                l[j] = (_Float16)(v - (float)h[j]);
            }
            const int off = ((s * 4 + kc) * 256 + t) * 16;
            *(half8*)(wsb + off) = h;
            *(half8*)(wsb + off + 32768) = l;
        }
    }
}

template <bool PREAT>
__global__ __launch_bounds__(256, 4)
void fused_constrain_mfma(const float* __restrict__ z,
                          const float* __restrict__ pivot,
                          const float* __restrict__ At,
                          const float* __restrict__ b,
                          const float* __restrict__ ws,
                          float* __restrict__ out) {
    __shared__ __align__(16) char lds[33280];

    const int tid  = threadIdx.x;
    const int lane = tid & 63;
    const int li   = lane & 31;          // tile col lane (B) / tile row (A)
    const int hi   = lane >> 5;          // k-half within 16-k step
    const int wid  = tid >> 6;
    const int rg   = wid >> 1;           // row group: rows rg*32..+32
    const int cg   = wid & 1;            // col group: cols cg*128..+128
    const int R0   = rg * 32;
    const int colbase = cg * 128;
    const int base = blockIdx.x * (BR * DIMK);

    // ---- z A-fragment loads (rows owned per-lane, both k-steps) ----
    float4 zf[8];
    {
        const float* zr = z + base + (R0 + li) * DIMK + hi * 8;
#pragma unroll
        for (int q = 0; q < 4; ++q) {            // q = s*2 + ksl
            const float* p = zr + (q >> 1) * 32 + (q & 1) * 16;
            zf[q * 2 + 0] = *(const float4*)(p);
            zf[q * 2 + 1] = *(const float4*)(p + 4);
        }
    }

    if constexpr (PREAT) {
        // fast path: park exact fp32 z in LDS for the epilogue (swizzled)
        const int zrow = R0 + li;
        const int rx = zrow & 15;
        char* zt = lds + LDS_ZT + zrow * 256;
#pragma unroll
        for (int q = 0; q < 4; ++q) {
            const int c0 = hi * 2 + (q >> 1) * 8 + (q & 1) * 4;  // chunk16 idx
            *(float4*)(zt + ((c0 ^ rx) << 4))       = zf[q * 2 + 0];
            *(float4*)(zt + (((c0 + 1) ^ rx) << 4)) = zf[q * 2 + 1];
        }
    } else {
        // fallback: stage At step 0 into LDS (round-3 proven path)
        const int swzT = (tid & 3) ^ ((tid >> 2) & 3);
#pragma unroll
        for (int kc = 0; kc < 4; ++kc) {
            float v[8];
#pragma unroll
            for (int j = 0; j < 8; ++j)
                v[j] = At[(kc * 8 + j) * MC + tid];
            half8 h, l;
#pragma unroll
            for (int j = 0; j < 8; ++j) {
                h[j] = (_Float16)v[j];
                l[j] = (_Float16)(v[j] - (float)h[j]);
            }
            const int off = tid * 64 + ((kc ^ swzT) << 4);
            *(half8*)(lds + LDS_AH + off) = h;
            *(half8*)(lds + LDS_AL + off) = l;
        }
    }

    // ---- convert z to fp16 hi/lo fragments ----
    half8 azh[4], azl[4];
    const float* zv = (const float*)zf;
#pragma unroll
    for (int q = 0; q < 4; ++q)
#pragma unroll
        for (int j = 0; j < 8; ++j) {
            const float v = zv[q * 8 + j];
            azh[q][j] = (_Float16)v;
            azl[q][j] = (_Float16)(v - (float)azh[q][j]);
        }

    f32x16 acc[4];
#pragma unroll
    for (int ct = 0; ct < 4; ++ct)
#pragma unroll
        for (int e = 0; e < 16; ++e) acc[ct][e] = 0.f;

    if constexpr (PREAT) {
        // ---- barrier-free GEMM: coalesced B-fragment loads from L2-hot ws ----
        // lane (hi,li) address = pb + s*16384 + ksl*8192 + ct*512 (+32768 lo);
        // within a load, li strides 16B -> one contiguous 512B run per half-wave
        const char* pb = (const char*)ws + WS_AT + (hi * 256 + colbase + li) * 16;
#pragma unroll
        for (int s = 0; s < 2; ++s)
#pragma unroll
            for (int ksl = 0; ksl < 2; ++ksl) {
                const half8 ah = azh[s * 2 + ksl], al = azl[s * 2 + ksl];
                const int ob = s * 16384 + ksl * 8192;
#pragma unroll
                for (int ct = 0; ct < 4; ++ct) {
                    const half8 bh = *(const half8*)(pb + ob + ct * 512);
                    const half8 bl = *(const half8*)(pb + ob + ct * 512 + 32768);
                    acc[ct] = __builtin_amdgcn_mfma_f32_32x32x16_f16(ah, bh, acc[ct], 0, 0, 0);
                    acc[ct] = __builtin_amdgcn_mfma_f32_32x32x16_f16(ah, bl, acc[ct], 0, 0, 0);
                    acc[ct] = __builtin_amdgcn_mfma_f32_32x32x16_f16(al, bh, acc[ct], 0, 0, 0);
                }
            }
    } else {
        // ---- fallback: two staged phases with barriers (round-3 verbatim) ----
        const int swz = (li & 3) ^ ((li >> 2) & 3);
        __syncthreads();
#pragma unroll
        for (int ksl = 0; ksl < 2; ++ksl) {
            const int cb = ((ksl * 2 + hi) ^ swz) << 4;
            const half8 ah = azh[ksl], al = azl[ksl];
#pragma unroll
            for (int ct = 0; ct < 4; ++ct) {
                const int off = (colbase + ct * 32 + li) * 64 + cb;
                const half8 bh = *(const half8*)(lds + LDS_AH + off);
                const half8 bl = *(const half8*)(lds + LDS_AL + off);
                acc[ct] = __builtin_amdgcn_mfma_f32_32x32x16_f16(ah, bh, acc[ct], 0, 0, 0);
                acc[ct] = __builtin_amdgcn_mfma_f32_32x32x16_f16(ah, bl, acc[ct], 0, 0, 0);
                acc[ct] = __builtin_amdgcn_mfma_f32_32x32x16_f16(al, bh, acc[ct], 0, 0, 0);
            }
        }
        __syncthreads();
        const int swzT = (tid & 3) ^ ((tid >> 2) & 3);
#pragma unroll
        for (int kc = 0; kc < 4; ++kc) {
            float v[8];
#pragma unroll
            for (int j = 0; j < 8; ++j)
                v[j] = At[(32 + kc * 8 + j) * MC + tid];
            half8 h, l;
#pragma unroll
            for (int j = 0; j < 8; ++j) {
                h[j] = (_Float16)v[j];
                l[j] = (_Float16)(v[j] - (float)h[j]);
            }
            const int off = tid * 64 + ((kc ^ swzT) << 4);
            *(half8*)(lds + LDS_AH + off) = h;
            *(half8*)(lds + LDS_AL + off) = l;
        }
        __syncthreads();
#pragma unroll
        for (int ksl = 0; ksl < 2; ++ksl) {
            const int cb = ((ksl * 2 + hi) ^ swz) << 4;
            const half8 ah = azh[2 + ksl], al = azl[2 + ksl];
#pragma unroll
            for (int ct = 0; ct < 4; ++ct) {
                const int off = (colbase + ct * 32 + li) * 64 + cb;
                const half8 bh = *(const half8*)(lds + LDS_AH + off);
                const half8 bl = *(const half8*)(lds + LDS_AL + off);
                acc[ct] = __builtin_amdgcn_mfma_f32_32x32x16_f16(ah, bh, acc[ct], 0, 0, 0);
                acc[ct] = __builtin_amdgcn_mfma_f32_32x32x16_f16(ah, bl, acc[ct], 0, 0, 0);
                acc[ct] = __builtin_amdgcn_mfma_f32_32x32x16_f16(al, bh, acc[ct], 0, 0, 0);
            }
        }
    }

    // ---- epilogue: masked alpha, intra-wave col-max, cross-wave combine ----
    float bv[4], cv[4];
#pragma unroll
    for (int ct = 0; ct < 4; ++ct) {
        const int c = colbase + ct * 32 + li;
        bv[ct] = b[c];
        cv[ct] = ws[c];                 // cvec (fp32)
    }
    float gm[16];
#pragma unroll
    for (int r = 0; r < 16; ++r) gm[r] = 0.f;
#pragma unroll
    for (int ct = 0; ct < 4; ++ct)
#pragma unroll
        for (int r = 0; r < 16; ++r) {
            const float sv = acc[ct][r];
            const float sa = sv - bv[ct];
            const float qd = fmaxf(sv - cv[ct], 1e-9f);
            // sa<0 gives negative alpha, excluded by fmax against gm>=0
            gm[r] = fmaxf(gm[r], sa * __builtin_amdgcn_rcpf(qd));
        }
#pragma unroll
    for (int r = 0; r < 16; ++r)
#pragma unroll
        for (int off = 1; off < 32; off <<= 1)   // reduce over 32 col-lanes
            gm[r] = fmaxf(gm[r], __shfl_xor(gm[r], off));

    float* gmbuf = (float*)(lds + (PREAT ? LDS_GM2 : LDS_GM));
#pragma unroll
    for (int r = 0; r < 16; ++r) {
        const int row = (r & 3) + 8 * (r >> 2) + 4 * hi;   // C/D row map
        if (li == 0) gmbuf[rg * 64 + row * 2 + cg] = gm[r];
    }
    __syncthreads();   // covers gmbuf and (fast path) z-tile visibility

    // cg0 stores rows R0+0..15 (its r 0..7), cg1 stores rows R0+16..31
    const float2 p2 = *(const float2*)(pivot + 2 * li);
    const int r0 = cg * 8;
#pragma unroll
    for (int rr = 0; rr < 8; ++rr) {
        const int r   = r0 + rr;
        const int row = (r & 3) + 8 * (r >> 2) + 4 * hi;
        const float g = fmaxf(gm[r], gmbuf[rg * 64 + row * 2 + (cg ^ 1)]);
        const int zrow = R0 + row;
        float2 zz;
        if constexpr (PREAT) {
            const int byt = LDS_ZT + zrow * 256 +
                            (((li >> 1) ^ (zrow & 15)) << 4) + (li & 1) * 8;
            zz = *(const float2*)(lds + byt);        // exact fp32 z from LDS
        } else {
            zz = *(const float2*)(z + base + zrow * DIMK + 2 * li);
        }
        float2 o;
        o.x = fmaf(g, p2.x - zz.x, zz.x);
        o.y = fmaf(g, p2.y - zz.y, zz.y);
        *(float2*)(out + base + zrow * DIMK + 2 * li) = o;
    }
}

extern "C" void kernel_launch(void* const* d_in, const int* in_sizes, int n_in,
                              void* d_out, int out_size, void* d_ws, size_t ws_size,
                              hipStream_t stream) {
    const float* z     = (const float*)d_in[0];
    const float* pivot = (const float*)d_in[1];
    const float* At    = (const float*)d_in[2];
    const float* b     = (const float*)d_in[3];
    float* ws = (float*)d_ws;
    if (ws_size >= (size_t)WS_NEED) {
        // fast path: pre-split At image in ws; barrier-free coalesced GEMM
        precompute_at<<<dim3(1), dim3(MC), 0, stream>>>(pivot, At, ws);
        fused_constrain_mfma<true><<<dim3(NB), dim3(256), 0, stream>>>(
            z, pivot, At, b, ws, (float*)d_out);
    } else {
        // safe path: only 1 KB of workspace (cvec); At split done per-block
        precompute_c<<<dim3(1), dim3(MC), 0, stream>>>(pivot, At, ws);
        fused_constrain_mfma<false><<<dim3(NB), dim3(256), 0, stream>>>(
            z, pivot, At, b, ws, (float*)d_out);
    }
}

// Round 6
// 156.892 us; speedup vs baseline: 1.2517x; 1.0290x over previous
//
#include <hip/hip_runtime.h>

#define DIMK 64
#define MC 256
#define BR 64                    // rows per tile
#define NROWS 262144
#define NT (NROWS / BR)          // 4096 tiles
#define PB 512                   // persistent blocks (2 per CU)
#define TPB (NT / PB)            // 8 tiles per block

// workspace layout (bytes):
//   [0, 1024)            cvec fp32 (256 floats)            [always]
//   [1024, 1024+65536)   At fp16 hi/lo image (fast path only, ws_size-guarded):
//     plane-major: hi-half at WS_AT + ((s*4 + kc)*256 + col)*16, kc = 2*ksl + hi
//     lo-half at +32768; j-th half of a chunk is k = s*32 + kc*8 + j
#define WS_AT 1024
#define WS_NEED (1024 + 65536)

// fallback-path LDS offsets (round-3 proven layout)
#define LDS_AH 0
#define LDS_AL 16384
#define LDS_GM 32768
#define LDS_FB_SIZE 33280
// fast-path LDS: At image [0,65536) + double-buffered gm [65536,66560)
#define LDS_GM3 65536
#define LDS_FP_SIZE 66560

typedef _Float16 half8 __attribute__((ext_vector_type(8)));
typedef float f32x16 __attribute__((ext_vector_type(16)));

// cvec only (1 KB ws — proven-safe footprint)
__global__ void precompute_c(const float* __restrict__ pivot,
                             const float* __restrict__ At,
                             float* __restrict__ ws) {
    const int t = threadIdx.x;
    float acc = 0.f;
#pragma unroll
    for (int k = 0; k < DIMK; ++k) acc = fmaf(pivot[k], At[k * MC + t], acc);
    ws[t] = acc;
}

// cvec + one-time At -> fp16 hi/lo split, plane-major image (fast path)
__global__ void precompute_at(const float* __restrict__ pivot,
                              const float* __restrict__ At,
                              float* __restrict__ ws) {
    const int t = threadIdx.x;              // column 0..255
    float col[DIMK];
    float acc = 0.f;
#pragma unroll
    for (int k = 0; k < DIMK; ++k) {
        col[k] = At[k * MC + t];            // coalesced across t
        acc = fmaf(pivot[k], col[k], acc);
    }
    ws[t] = acc;                            // cvec, fp32
    char* wsb = (char*)ws + WS_AT;
#pragma unroll
    for (int s = 0; s < 2; ++s) {
#pragma unroll
        for (int kc = 0; kc < 4; ++kc) {
            half8 h, l;
#pragma unroll
            for (int j = 0; j < 8; ++j) {
                const float v = col[s * 32 + kc * 8 + j];
                h[j] = (_Float16)v;
                l[j] = (_Float16)(v - (float)h[j]);
            }
            const int off = ((s * 4 + kc) * 256 + t) * 16;
            *(half8*)(wsb + off) = h;
            *(half8*)(wsb + off + 32768) = l;
        }
    }
}

template <bool PREAT>
__global__ __launch_bounds__(256, 2)
void fused_constrain_mfma(const float* __restrict__ z,
                          const float* __restrict__ pivot,
                          const float* __restrict__ At,
                          const float* __restrict__ b,
                          const float* __restrict__ ws,
                          float* __restrict__ out) {
    extern __shared__ __align__(16) char lds[];

    const int tid  = threadIdx.x;
    const int lane = tid & 63;
    const int li   = lane & 31;          // tile col lane (B) / tile row (A)
    const int hi   = lane >> 5;          // k-half within 16-k step
    const int wid  = tid >> 6;
    const int rg   = wid >> 1;           // row group: rows rg*32..+32
    const int cg   = wid & 1;            // col group: cols cg*128..+128
    const int R0   = rg * 32;
    const int colbase = cg * 128;

    if constexpr (PREAT) {
        // ---- loop-invariant per-thread constants ----
        float bv[4], cv[4];
#pragma unroll
        for (int ct = 0; ct < 4; ++ct) {
            const int c = colbase + ct * 32 + li;
            bv[ct] = b[c];
            cv[ct] = ws[c];              // cvec fp32
        }
        const float2 p2 = *(const float2*)(pivot + 2 * li);

        // ---- issue tile-0 z loads (hidden under At staging) ----
        float4 zfA[8], zfB[8];
        {
            const float* zr = z + blockIdx.x * (TPB * BR * DIMK) +
                              (R0 + li) * DIMK + hi * 8;
#pragma unroll
            for (int q = 0; q < 4; ++q) {
                const float* p = zr + (q >> 1) * 32 + (q & 1) * 16;
                zfA[q * 2 + 0] = *(const float4*)(p);
                zfA[q * 2 + 1] = *(const float4*)(p + 4);
            }
        }

        // ---- stage the full 64 KB At image into LDS ONCE ----
        {
            const char* wsA = (const char*)ws + WS_AT;
#pragma unroll
            for (int p = 0; p < 16; ++p) {
                const int f = p * 256 + tid;
                *(float4*)(lds + f * 16) = *(const float4*)(wsA + f * 16);
            }
        }
        __syncthreads();

        const int Boff = hi * 4096 + (colbase + li) * 16;

        // ---- per-tile body (zc = current z regs, zn = prefetch target) ----
        auto tile_body = [&](float4 (&zc)[8], float4 (&zn)[8],
                             const int i, const bool pf) {
            const int tbase = (blockIdx.x * TPB + i) * (BR * DIMK);

            // prefetch next tile's z (consumed next call; ~2400 cy window)
            if (pf) {
                const float* zr = z + tbase + BR * DIMK +
                                  (R0 + li) * DIMK + hi * 8;
#pragma unroll
                for (int q = 0; q < 4; ++q) {
                    const float* p = zr + (q >> 1) * 32 + (q & 1) * 16;
                    zn[q * 2 + 0] = *(const float4*)(p);
                    zn[q * 2 + 1] = *(const float4*)(p + 4);
                }
            }

            // convert current z to fp16 hi/lo fragments
            half8 azh[4], azl[4];
            const float* zv = (const float*)zc;
#pragma unroll
            for (int q = 0; q < 4; ++q)
#pragma unroll
                for (int j = 0; j < 8; ++j) {
                    const float v = zv[q * 8 + j];
                    azh[q][j] = (_Float16)v;
                    azl[q][j] = (_Float16)(v - (float)azh[q][j]);
                }

            f32x16 acc[4];
#pragma unroll
            for (int ct = 0; ct < 4; ++ct)
#pragma unroll
                for (int e = 0; e < 16; ++e) acc[ct][e] = 0.f;

            // S += zh@ah + zh@al + zl@ah, B fragments from LDS (conflict-free)
#pragma unroll
            for (int s = 0; s < 2; ++s)
#pragma unroll
                for (int ksl = 0; ksl < 2; ++ksl) {
                    const half8 ah = azh[s * 2 + ksl], al = azl[s * 2 + ksl];
                    const int ob = Boff + s * 16384 + ksl * 8192;
#pragma unroll
                    for (int ct = 0; ct < 4; ++ct) {
                        const half8 bh = *(const half8*)(lds + ob + ct * 512);
                        const half8 bl = *(const half8*)(lds + ob + ct * 512 + 32768);
                        acc[ct] = __builtin_amdgcn_mfma_f32_32x32x16_f16(ah, bh, acc[ct], 0, 0, 0);
                        acc[ct] = __builtin_amdgcn_mfma_f32_32x32x16_f16(ah, bl, acc[ct], 0, 0, 0);
                        acc[ct] = __builtin_amdgcn_mfma_f32_32x32x16_f16(al, bh, acc[ct], 0, 0, 0);
                    }
                }

            // epilogue: masked alpha, col-max over 32 lanes, cross-wave combine
            float gm[16];
#pragma unroll
            for (int r = 0; r < 16; ++r) gm[r] = 0.f;
#pragma unroll
            for (int ct = 0; ct < 4; ++ct)
#pragma unroll
                for (int r = 0; r < 16; ++r) {
                    const float sv = acc[ct][r];
                    const float sa = sv - bv[ct];
                    const float qd = fmaxf(sv - cv[ct], 1e-9f);
                    gm[r] = fmaxf(gm[r], sa * __builtin_amdgcn_rcpf(qd));
                }
#pragma unroll
            for (int r = 0; r < 16; ++r)
#pragma unroll
                for (int off = 1; off < 32; off <<= 1)
                    gm[r] = fmaxf(gm[r], __shfl_xor(gm[r], off));

            float* gmb = (float*)(lds + LDS_GM3 + ((i & 1) << 9));  // dbuf
#pragma unroll
            for (int r = 0; r < 16; ++r) {
                const int row = (r & 3) + 8 * (r >> 2) + 4 * hi;    // C/D row map
                if (li == 0) gmb[rg * 64 + row * 2 + cg] = gm[r];
            }
            __syncthreads();   // only barrier per tile (gmbuf visibility)

            const int r0 = cg * 8;
#pragma unroll
            for (int rr = 0; rr < 8; ++rr) {
                const int r   = r0 + rr;
                const int row = (r & 3) + 8 * (r >> 2) + 4 * hi;
                const float g = fmaxf(gm[r], gmb[rg * 64 + row * 2 + (cg ^ 1)]);
                const int idx = tbase + (R0 + row) * DIMK + 2 * li;
                const float2 zz = *(const float2*)(z + idx);  // L1/L2-hot exact z
                float2 o;
                o.x = fmaf(g, p2.x - zz.x, zz.x);
                o.y = fmaf(g, p2.y - zz.y, zz.y);
                *(float2*)(out + idx) = o;
            }
        };

#pragma clang loop unroll(disable)
        for (int j = 0; j < TPB / 2; ++j) {
            tile_body(zfA, zfB, 2 * j, true);
            tile_body(zfB, zfA, 2 * j + 1, j < TPB / 2 - 1);
        }
    } else {
        // ================= fallback: round-3 proven path =================
        const int base = blockIdx.x * (BR * DIMK);
        float4 zf[8];
        {
            const float* zr = z + base + (R0 + li) * DIMK + hi * 8;
#pragma unroll
            for (int q = 0; q < 4; ++q) {
                const float* p = zr + (q >> 1) * 32 + (q & 1) * 16;
                zf[q * 2 + 0] = *(const float4*)(p);
                zf[q * 2 + 1] = *(const float4*)(p + 4);
            }
        }
        const int swzT = (tid & 3) ^ ((tid >> 2) & 3);
#pragma unroll
        for (int kc = 0; kc < 4; ++kc) {
            float v[8];
#pragma unroll
            for (int j = 0; j < 8; ++j) v[j] = At[(kc * 8 + j) * MC + tid];
            half8 h, l;
#pragma unroll
            for (int j = 0; j < 8; ++j) {
                h[j] = (_Float16)v[j];
                l[j] = (_Float16)(v[j] - (float)h[j]);
            }
            const int off = tid * 64 + ((kc ^ swzT) << 4);
            *(half8*)(lds + LDS_AH + off) = h;
            *(half8*)(lds + LDS_AL + off) = l;
        }

        half8 azh[4], azl[4];
        const float* zv = (const float*)zf;
#pragma unroll
        for (int q = 0; q < 4; ++q)
#pragma unroll
            for (int j = 0; j < 8; ++j) {
                const float v = zv[q * 8 + j];
                azh[q][j] = (_Float16)v;
                azl[q][j] = (_Float16)(v - (float)azh[q][j]);
            }

        f32x16 acc[4];
#pragma unroll
        for (int ct = 0; ct < 4; ++ct)
#pragma unroll
            for (int e = 0; e < 16; ++e) acc[ct][e] = 0.f;

        const int swz = (li & 3) ^ ((li >> 2) & 3);
        __syncthreads();
#pragma unroll
        for (int ksl = 0; ksl < 2; ++ksl) {
            const int cb = ((ksl * 2 + hi) ^ swz) << 4;
            const half8 ah = azh[ksl], al = azl[ksl];
#pragma unroll
            for (int ct = 0; ct < 4; ++ct) {
                const int off = (colbase + ct * 32 + li) * 64 + cb;
                const half8 bh = *(const half8*)(lds + LDS_AH + off);
                const half8 bl = *(const half8*)(lds + LDS_AL + off);
                acc[ct] = __builtin_amdgcn_mfma_f32_32x32x16_f16(ah, bh, acc[ct], 0, 0, 0);
                acc[ct] = __builtin_amdgcn_mfma_f32_32x32x16_f16(ah, bl, acc[ct], 0, 0, 0);
                acc[ct] = __builtin_amdgcn_mfma_f32_32x32x16_f16(al, bh, acc[ct], 0, 0, 0);
            }
        }
        __syncthreads();
#pragma unroll
        for (int kc = 0; kc < 4; ++kc) {
            float v[8];
#pragma unroll
            for (int j = 0; j < 8; ++j) v[j] = At[(32 + kc * 8 + j) * MC + tid];
            half8 h, l;
#pragma unroll
            for (int j = 0; j < 8; ++j) {
                h[j] = (_Float16)v[j];
                l[j] = (_Float16)(v[j] - (float)h[j]);
            }
            const int off = tid * 64 + ((kc ^ swzT) << 4);
            *(half8*)(lds + LDS_AH + off) = h;
            *(half8*)(lds + LDS_AL + off) = l;
        }
        __syncthreads();
#pragma unroll
        for (int ksl = 0; ksl < 2; ++ksl) {
            const int cb = ((ksl * 2 + hi) ^ swz) << 4;
            const half8 ah = azh[2 + ksl], al = azl[2 + ksl];
#pragma unroll
            for (int ct = 0; ct < 4; ++ct) {
                const int off = (colbase + ct * 32 + li) * 64 + cb;
                const half8 bh = *(const half8*)(lds + LDS_AH + off);
                const half8 bl = *(const half8*)(lds + LDS_AL + off);
                acc[ct] = __builtin_amdgcn_mfma_f32_32x32x16_f16(ah, bh, acc[ct], 0, 0, 0);
                acc[ct] = __builtin_amdgcn_mfma_f32_32x32x16_f16(ah, bl, acc[ct], 0, 0, 0);
                acc[ct] = __builtin_amdgcn_mfma_f32_32x32x16_f16(al, bh, acc[ct], 0, 0, 0);
            }
        }

        float bv[4], cv[4];
#pragma unroll
        for (int ct = 0; ct < 4; ++ct) {
            const int c = colbase + ct * 32 + li;
            bv[ct] = b[c];
            cv[ct] = ws[c];
        }
        float gm[16];
#pragma unroll
        for (int r = 0; r < 16; ++r) gm[r] = 0.f;
#pragma unroll
        for (int ct = 0; ct < 4; ++ct)
#pragma unroll
            for (int r = 0; r < 16; ++r) {
                const float sv = acc[ct][r];
                const float sa = sv - bv[ct];
                const float qd = fmaxf(sv - cv[ct], 1e-9f);
                gm[r] = fmaxf(gm[r], sa * __builtin_amdgcn_rcpf(qd));
            }
#pragma unroll
        for (int r = 0; r < 16; ++r)
#pragma unroll
            for (int off = 1; off < 32; off <<= 1)
                gm[r] = fmaxf(gm[r], __shfl_xor(gm[r], off));

        float* gmbuf = (float*)(lds + LDS_GM);
#pragma unroll
        for (int r = 0; r < 16; ++r) {
            const int row = (r & 3) + 8 * (r >> 2) + 4 * hi;
            if (li == 0) gmbuf[rg * 64 + row * 2 + cg] = gm[r];
        }
        __syncthreads();

        const float2 p2 = *(const float2*)(pivot + 2 * li);
        const int r0 = cg * 8;
#pragma unroll
        for (int rr = 0; rr < 8; ++rr) {
            const int r   = r0 + rr;
            const int row = (r & 3) + 8 * (r >> 2) + 4 * hi;
            const float g = fmaxf(gm[r], gmbuf[rg * 64 + row * 2 + (cg ^ 1)]);
            const int idx = base + (R0 + row) * DIMK + 2 * li;
            const float2 zz = *(const float2*)(z + idx);
            float2 o;
            o.x = fmaf(g, p2.x - zz.x, zz.x);
            o.y = fmaf(g, p2.y - zz.y, zz.y);
            *(float2*)(out + idx) = o;
        }
    }
}

extern "C" void kernel_launch(void* const* d_in, const int* in_sizes, int n_in,
                              void* d_out, int out_size, void* d_ws, size_t ws_size,
                              hipStream_t stream) {
    const float* z     = (const float*)d_in[0];
    const float* pivot = (const float*)d_in[1];
    const float* At    = (const float*)d_in[2];
    const float* b     = (const float*)d_in[3];
    float* ws = (float*)d_ws;
    if (ws_size >= (size_t)WS_NEED) {
        // fast path: persistent blocks, At staged to LDS once, z prefetch
        precompute_at<<<dim3(1), dim3(MC), 0, stream>>>(pivot, At, ws);
        fused_constrain_mfma<true><<<dim3(PB), dim3(256), LDS_FP_SIZE, stream>>>(
            z, pivot, At, b, ws, (float*)d_out);
    } else {
        // safe path: 1 KB ws (cvec); per-block At split (round-3 proven)
        precompute_c<<<dim3(1), dim3(MC), 0, stream>>>(pivot, At, ws);
        fused_constrain_mfma<false><<<dim3(NT), dim3(256), LDS_FB_SIZE, stream>>>(
            z, pivot, At, b, ws, (float*)d_out);
    }
}